// Round 8
// baseline (896.375 us; speedup 1.0000x reference)
//
#include <hip/hip_runtime.h>
#include <cstdint>

namespace {

constexpr int kT = 2048;
constexpr int kTok = 16384;
constexpr int kD = 512;
constexpr int kK = 1024;

typedef __attribute__((ext_vector_type(8))) short short8;   // 8 bf16 (4 VGPR)
typedef __attribute__((ext_vector_type(4))) float f32x4;

// ---------- helpers ----------
__device__ __forceinline__ float bf2f(uint16_t u) {
  union { uint32_t i; float f; } c; c.i = ((uint32_t)u) << 16; return c.f;
}
__device__ __forceinline__ uint16_t f2bf(float x) {
  union { float f; uint32_t i; } c; c.f = x;
  uint32_t lsb = (c.i >> 16) & 1u;
  return (uint16_t)((c.i + 0x7FFFu + lsb) >> 16);
}
__device__ __forceinline__ float gelu_f(float v) {
  return 0.5f * v * (1.0f + erff(v * 0.70710678118654752440f));
}
__device__ __forceinline__ uint32_t rotl32(uint32_t x, int r) {
  return (x << r) | (x >> (32 - r));
}

// Threefry-2x32, 20 rounds — bit-exact jax threefry (verified absmax=0 R2-R7)
__device__ __forceinline__ void tf2x32(uint32_t k0, uint32_t k1,
                                       uint32_t x0, uint32_t x1,
                                       uint32_t& o0, uint32_t& o1) {
  const uint32_t k2 = k0 ^ k1 ^ 0x1BD11BDAu;
  x0 += k0; x1 += k1;
#define TF_R(r) { x0 += x1; x1 = rotl32(x1, (r)); x1 ^= x0; }
  TF_R(13) TF_R(15) TF_R(26) TF_R(6)
  x0 += k1; x1 += k2 + 1u;
  TF_R(17) TF_R(29) TF_R(16) TF_R(24)
  x0 += k2; x1 += k0 + 2u;
  TF_R(13) TF_R(15) TF_R(26) TF_R(6)
  x0 += k0; x1 += k1 + 3u;
  TF_R(17) TF_R(29) TF_R(16) TF_R(24)
  x0 += k1; x1 += k2 + 4u;
  TF_R(13) TF_R(15) TF_R(26) TF_R(6)
  x0 += k2; x1 += k0 + 5u;
#undef TF_R
  o0 = x0; o1 = x1;
}

__device__ __forceinline__ float gumbel_bits(uint32_t bits) {
  float f = __uint_as_float((bits >> 9) | 0x3f800000u) - 1.0f;
  const float tiny = 1.17549435e-38f;
  float u = fmaxf(tiny, f + tiny);
  return -__logf(-__logf(u));
}
// gumbel in [-4.4698, 16.6356] by construction -> spread 21.1053; score =
// d*10 + g => codes with d < dmax - 2.11053 can never win. Filter at 2.2.

// ---------- dtype detection (unchanged; passed R2-R7) ----------
__global__ __launch_bounds__(256) void detect_kernel(const uint32_t* __restrict__ w,
                                                     uint32_t* __restrict__ flag) {
  __shared__ int red[256];
  int c = 0;
#pragma unroll
  for (int j = 0; j < 16; ++j) {
    uint32_t v = w[threadIdx.x * 16 + j];
    uint32_t e0 = (v >> 7) & 0xFFu;
    c += (e0 >= 100u && e0 <= 130u) ? 1 : 0;
  }
  red[threadIdx.x] = c;
  __syncthreads();
  for (int st = 128; st > 0; st >>= 1) {
    if (threadIdx.x < st) red[threadIdx.x] += red[threadIdx.x + st];
    __syncthreads();
  }
  if (threadIdx.x == 0) flag[0] = (red[0] > 2048) ? 1u : 0u;  // 1 = bf16
}

__device__ __forceinline__ float load_flag(const void* src, size_t i, uint32_t fl) {
  return fl ? bf2f(((const uint16_t*)src)[i]) : ((const float*)src)[i];
}

__global__ __launch_bounds__(256) void cvt_f32_kernel(const void* __restrict__ src,
                                                      float* __restrict__ dst, int n,
                                                      const uint32_t* __restrict__ flag) {
  int i = blockIdx.x * 256 + threadIdx.x;
  if (i >= n) return;
  dst[i] = load_flag(src, i, flag[0]);
}

__global__ __launch_bounds__(256) void cvt_bf16_kernel(const void* __restrict__ src,
                                                       uint16_t* __restrict__ dst, int n,
                                                       const uint32_t* __restrict__ flag) {
  int i = blockIdx.x * 256 + threadIdx.x;
  if (i >= n) return;
  if (flag[0]) dst[i] = ((const uint16_t*)src)[i];
  else         dst[i] = f2bf(((const float*)src)[i]);
}

// pack conv weights [CO][CI][3] -> bf16 tap-split [3][COP][CIP], zero-padded
__global__ __launch_bounds__(256) void pack_w_kernel(
    const void* __restrict__ src, uint16_t* __restrict__ dst,
    int CO, int CI, int COP, int CIP, const uint32_t* __restrict__ flag) {
  int i = blockIdx.x * 256 + threadIdx.x;
  int n = 3 * COP * CIP;
  if (i >= n) return;
  int tap = i / (COP * CIP);
  int rem = i - tap * COP * CIP;
  int co = rem / CIP, ci = rem - co * CIP;
  uint16_t v = 0;
  if (co < CO && ci < CI) {
    float f = load_flag(src, ((size_t)co * CI + ci) * 3 + tap, flag[0]);
    v = f2bf(f);
  }
  dst[i] = v;
}

// pack x [16384][100] (flag dtype) -> bf16 [16384][128] zero-padded
__global__ __launch_bounds__(256) void pack_x_kernel(const void* __restrict__ src,
                                                     uint16_t* __restrict__ dst,
                                                     const uint32_t* __restrict__ flag) {
  int i = blockIdx.x * 256 + threadIdx.x;  // over 16384*128
  int tok = i >> 7, ci = i & 127;
  uint16_t v = 0;
  if (ci < 100) {
    float f = load_flag(src, (size_t)tok * 100 + ci, flag[0]);
    v = f2bf(f);
  }
  dst[i] = v;
}

// dec_in (in place): r <- bf16(z - r), over 16384*512 elems, x4 vectorized
__global__ __launch_bounds__(256) void dec_in_kernel(const uint16_t* __restrict__ z,
                                                     uint16_t* __restrict__ r) {
  int i = blockIdx.x * 256 + threadIdx.x;
  uint2 zp = ((const uint2*)z)[i];
  uint2 rp = ((uint2*)r)[i];
  union { uint16_t u[4]; uint2 v; } zi, ri, out;
  zi.v = zp; ri.v = rp;
  out.u[0] = f2bf(bf2f(zi.u[0]) - bf2f(ri.u[0]));
  out.u[1] = f2bf(bf2f(zi.u[1]) - bf2f(ri.u[1]));
  out.u[2] = f2bf(bf2f(zi.u[2]) - bf2f(ri.u[2]));
  out.u[3] = f2bf(bf2f(zi.u[3]) - bf2f(ri.u[3]));
  ((uint2*)r)[i] = out.v;
}

// ---------- codebook squared norms ----------
__global__ __launch_bounds__(256) void csq_kernel(const float* __restrict__ cb,
                                                  float* __restrict__ c_sq) {
  const int lane = threadIdx.x & 63;
  const int k = blockIdx.x * 4 + (threadIdx.x >> 6);
  const float* row = cb + (size_t)k * kD;
  float s = 0.f;
#pragma unroll
  for (int j = 0; j < 8; ++j) {
    float v = row[lane + 64 * j];
    s = fmaf(v, v, s);
  }
  for (int off = 32; off > 0; off >>= 1) s += __shfl_down(s, off, 64);
  if (lane == 0) c_sq[k] = s;
}

// ---------- MFMA conv (+GELU), verified R4-R7 (absmax 0.0), unchanged ----------
template <int CIP, int COP, int CO_REAL, int OMODE>
__global__ __launch_bounds__(256) void conv_mfma_kernel(
    const uint16_t* __restrict__ A, const uint16_t* __restrict__ W,
    const float* __restrict__ bias, uint16_t* __restrict__ outb,
    float* __restrict__ outf, const void* __restrict__ xraw,
    const uint32_t* __restrict__ flag, float* __restrict__ partial) {
  constexpr int AST = CIP + 8;
  __shared__ uint16_t As[66 * AST];
  __shared__ uint16_t Bs[128 * 72];
  __shared__ float red[256];

  const int tid = threadIdx.x;
  const int w = tid >> 6;
  const int lane = tid & 63;
  const int quad = lane >> 4;
  const int col = lane & 15;
  const int tok0 = blockIdx.x * 64;
  const int t0 = tok0 & (kT - 1);

  constexpr int AV = 66 * (CIP / 8);
  for (int m = tid; m < AV; m += 256) {
    int r = m / (CIP / 8), c8 = m % (CIP / 8);
    bool valid = !((r == 0 && t0 == 0) || (r == 65 && t0 == kT - 64));
    uint4 v = {0, 0, 0, 0};
    if (valid) v = *(const uint4*)(A + (size_t)(tok0 - 1 + r) * CIP + c8 * 8);
    *(uint4*)(As + r * AST + c8 * 8) = v;
  }

  float part = 0.f;
#pragma unroll 1
  for (int chunk = 0; chunk < COP / 128; ++chunk) {
    f32x4 acc[4][2];
#pragma unroll
    for (int mt = 0; mt < 4; ++mt)
#pragma unroll
      for (int nt = 0; nt < 2; ++nt) acc[mt][nt] = (f32x4){0.f, 0.f, 0.f, 0.f};

#pragma unroll 1
    for (int tap = 0; tap < 3; ++tap) {
#pragma unroll 1
      for (int kt = 0; kt < CIP / 64; ++kt) {
        __syncthreads();
#pragma unroll
        for (int it = 0; it < 4; ++it) {
          int m = it * 256 + tid;
          int rr = m >> 3, c8 = m & 7;
          *(uint4*)(Bs + rr * 72 + c8 * 8) =
              *(const uint4*)(W + ((size_t)tap * COP + chunk * 128 + rr) * CIP + kt * 64 + c8 * 8);
        }
        __syncthreads();
#pragma unroll
        for (int kk = 0; kk < 2; ++kk) {
          short8 bf0 = *(const short8*)(Bs + (w * 32 + col) * 72 + kk * 32 + quad * 8);
          short8 bf1 = *(const short8*)(Bs + (w * 32 + 16 + col) * 72 + kk * 32 + quad * 8);
#pragma unroll
          for (int mt = 0; mt < 4; ++mt) {
            short8 af = *(const short8*)(As + (mt * 16 + col + tap) * AST + kt * 64 + kk * 32 + quad * 8);
            acc[mt][0] = __builtin_amdgcn_mfma_f32_16x16x32_bf16(af, bf0, acc[mt][0], 0, 0, 0);
            acc[mt][1] = __builtin_amdgcn_mfma_f32_16x16x32_bf16(af, bf1, acc[mt][1], 0, 0, 0);
          }
        }
      }
    }
#pragma unroll
    for (int nt = 0; nt < 2; ++nt) {
      const int co = chunk * 128 + w * 32 + nt * 16 + col;
      const float bv = (OMODE == 2 && co >= CO_REAL) ? 0.f : bias[co];
#pragma unroll
      for (int mt = 0; mt < 4; ++mt) {
#pragma unroll
        for (int rg = 0; rg < 4; ++rg) {
          const int token = tok0 + mt * 16 + quad * 4 + rg;
          float g = gelu_f(acc[mt][nt][rg] + bv);
          if constexpr (OMODE == 0) {
            outb[(size_t)token * CO_REAL + co] = f2bf(g);
          } else if constexpr (OMODE == 1) {
            outf[(size_t)token * CO_REAL + co] = g;
            outb[(size_t)token * CO_REAL + co] = f2bf(g);
          } else {
            if (co < CO_REAL) {
              float xv = load_flag(xraw, (size_t)token * CO_REAL + co, flag[0]);
              float d = xv - g;
              part += d * d;
            }
          }
        }
      }
    }
  }
  if constexpr (OMODE == 2) {
    red[tid] = part;
    __syncthreads();
    for (int st = 128; st > 0; st >>= 1) {
      if (tid < st) red[tid] += red[tid + st];
      __syncthreads();
    }
    if (tid == 0) partial[blockIdx.x] = red[0];
  }
}

// ---------- VQ stage: 2-pass barrier-free GEMM, 4-deep B prefetch ring ----------
// 512 blocks x 256 thr (4 waves), 32 tokens/block (16 + 16 paired halves).
// Codes split into 2 passes of 512: acc shrinks 128->64 VGPRs, freeing room
// for a 4-deep register ring of B-fragments (loads issued 3 steps ~230 cyc
// ahead of use >= ~200 cyc L2 latency -> latency hidden; R7's depth-1 ring
// exposed ~120 cyc/step). Running per-token dmax in LDS gives a pass-local
// filter threshold <= global threshold => candidate superset => argmax exact.
// bf16 state in/out (R6/R7-verified).
__global__ __launch_bounds__(256, 2) void vq_stage_kernel(
    const uint16_t* __restrict__ Ain, uint16_t* __restrict__ Aout,
    const uint16_t* __restrict__ cbh, const float* __restrict__ cbf,
    const float* __restrict__ csqG, float* __restrict__ cp,
    uint32_t key0, uint32_t key1) {
  constexpr int AST = 528;
  __shared__ uint16_t As[32 * AST];   // 33,792 B
  __shared__ float csqS[1024];        // 4 KB
  __shared__ float dmaxW[32 * 4];
  __shared__ float dmaxS[32];         // running per-token dmax across passes
  __shared__ float wredV[32 * 4];
  __shared__ int   wredI[32 * 4];
  __shared__ int   idxS[32];
  __shared__ float cred[256];

  const int tid = threadIdx.x;
  const int w = tid >> 6;
  const int lane = tid & 63;
  const int quad = lane >> 4;
  const int col = lane & 15;
  const int blk = blockIdx.x;
  const int tokA = blk * 16;
  const int tokB = 8192 + blk * 16;

  ((f32x4*)csqS)[tid] = ((const f32x4*)csqG)[tid];
  if (tid < 32) dmaxS[tid] = -INFINITY;

  // stage A: 32 rows x 512 bf16 (rows 0-15 first half, 16-31 second half)
#pragma unroll
  for (int it = 0; it < 8; ++it) {
    int m = it * 256 + tid;
    int r = m >> 6, c8 = m & 63;
    int token = (r < 16) ? (tokA + r) : (tokB + r - 16);
    *(uint4*)(As + r * AST + c8 * 8) =
        *(const uint4*)(Ain + (size_t)token * 512 + c8 * 8);
  }
  __syncthreads();

  float bestV[2][4];
  int bestI[2][4];
#pragma unroll
  for (int mt = 0; mt < 2; ++mt)
#pragma unroll
    for (int rg = 0; rg < 4; ++rg) { bestV[mt][rg] = -INFINITY; bestI[mt][rg] = 0; }

#pragma unroll 1
  for (int p = 0; p < 2; ++p) {
    const uint16_t* bb = cbh + (size_t)p * 262144 + (size_t)(w * 64 + col) * 512 + quad * 8;

    f32x4 acc[2][2][4];  // [chunk][mt][nt]
#pragma unroll
    for (int c = 0; c < 2; ++c)
#pragma unroll
      for (int mt = 0; mt < 2; ++mt)
#pragma unroll
        for (int nt = 0; nt < 4; ++nt) acc[c][mt][nt] = (f32x4){0.f, 0.f, 0.f, 0.f};

    // ---- GEMM: 32 steps, B-frags direct from L2, ring depth 4 ----
    short8 bf[4][4];
#pragma unroll
    for (int s = 0; s < 3; ++s)
#pragma unroll
      for (int nt = 0; nt < 4; ++nt)
        bf[s][nt] = *(const short8*)(bb + (size_t)(s >> 4) * 131072 + (s & 15) * 32 + nt * 8192);

#pragma unroll
    for (int G = 0; G < 32; ++G) {
      if (G < 29) {
        const int s = G + 3;
#pragma unroll
        for (int nt = 0; nt < 4; ++nt)
          bf[s & 3][nt] = *(const short8*)(bb + (size_t)(s >> 4) * 131072 + (s & 15) * 32 + nt * 8192);
      }
      const int chunk = G >> 4;
      const int koff = (G & 15) * 32 + quad * 8;
      short8 a0 = *(const short8*)(As + col * AST + koff);
      short8 a1 = *(const short8*)(As + (col + 16) * AST + koff);
#pragma unroll
      for (int nt = 0; nt < 4; ++nt) {
        acc[chunk][0][nt] = __builtin_amdgcn_mfma_f32_16x16x32_bf16(a0, bf[G & 3][nt], acc[chunk][0][nt], 0, 0, 0);
        acc[chunk][1][nt] = __builtin_amdgcn_mfma_f32_16x16x32_bf16(a1, bf[G & 3][nt], acc[chunk][1][nt], 0, 0, 0);
      }
    }

    // ---- pass dmax: regs -> 16-lane shfl -> LDS over 4 waves -> running ----
    float dmx[2][4];
#pragma unroll
    for (int mt = 0; mt < 2; ++mt)
#pragma unroll
      for (int rg = 0; rg < 4; ++rg) dmx[mt][rg] = -INFINITY;
#pragma unroll
    for (int c = 0; c < 2; ++c)
#pragma unroll
      for (int nt = 0; nt < 4; ++nt) {
        const int code = p * 512 + c * 256 + w * 64 + nt * 16 + col;
        const float csqv = csqS[code];
#pragma unroll
        for (int rg = 0; rg < 4; ++rg) {
          dmx[0][rg] = fmaxf(dmx[0][rg], acc[c][0][nt][rg] * 2.f - csqv);
          dmx[1][rg] = fmaxf(dmx[1][rg], acc[c][1][nt][rg] * 2.f - csqv);
        }
      }
#pragma unroll
    for (int mt = 0; mt < 2; ++mt)
#pragma unroll
      for (int rg = 0; rg < 4; ++rg) {
        float v = dmx[mt][rg];
#pragma unroll
        for (int m = 8; m >= 1; m >>= 1) v = fmaxf(v, __shfl_xor(v, m));
        if (col == 0) dmaxW[(mt * 16 + quad * 4 + rg) * 4 + w] = v;
      }
    __syncthreads();
    if (tid < 32) {
      float v = dmaxW[tid * 4];
#pragma unroll
      for (int j = 1; j < 4; ++j) v = fmaxf(v, dmaxW[tid * 4 + j]);
      dmaxS[tid] = fmaxf(dmaxS[tid], v);
    }
    __syncthreads();

    float thr0[4], thr1[4];
#pragma unroll
    for (int rg = 0; rg < 4; ++rg) {
      thr0[rg] = dmaxS[quad * 4 + rg] - 2.2f;
      thr1[rg] = dmaxS[16 + quad * 4 + rg] - 2.2f;
    }

    // ---- filtered gumbel + per-lane running argmax (codes ascending) ----
#pragma unroll
    for (int c = 0; c < 2; ++c)
#pragma unroll
      for (int nt = 0; nt < 4; ++nt) {
        const int code = p * 512 + c * 256 + w * 64 + nt * 16 + col;
        const float csqv = csqS[code];
#pragma unroll
        for (int rg = 0; rg < 4; ++rg) {
          float d0 = acc[c][0][nt][rg] * 2.f - csqv;
          float d1 = acc[c][1][nt][rg] * 2.f - csqv;
          bool c0 = d0 >= thr0[rg];
          bool c1 = d1 >= thr1[rg];
          if (c0 || c1) {
            const uint32_t n = (uint32_t)(tokA + quad * 4 + rg) * 1024u + (uint32_t)code;
            uint32_t o0, o1;
            tf2x32(key0, key1, n, n + 8388608u, o0, o1);
            if (c0) {
              float s0 = d0 * 10.f + gumbel_bits(o0);
              if (s0 > bestV[0][rg]) { bestV[0][rg] = s0; bestI[0][rg] = code; }
            }
            if (c1) {
              float s1 = d1 * 10.f + gumbel_bits(o1);
              if (s1 > bestV[1][rg]) { bestV[1][rg] = s1; bestI[1][rg] = code; }
            }
          }
        }
      }
  }

  // 16-lane shfl argmax (tie: smaller code), then cross-wave via LDS
#pragma unroll
  for (int mt = 0; mt < 2; ++mt)
#pragma unroll
    for (int rg = 0; rg < 4; ++rg) {
      float v = bestV[mt][rg];
      int i = bestI[mt][rg];
#pragma unroll
      for (int m = 8; m >= 1; m >>= 1) {
        float vo = __shfl_xor(v, m);
        int io = __shfl_xor(i, m);
        if (vo > v || (vo == v && io < i)) { v = vo; i = io; }
      }
      if (col == 0) {
        const int row = mt * 16 + quad * 4 + rg;
        wredV[row * 4 + w] = v;
        wredI[row * 4 + w] = i;
      }
    }
  __syncthreads();
  if (tid < 32) {
    float v = wredV[tid * 4];
    int i = wredI[tid * 4];
#pragma unroll
    for (int j = 1; j < 4; ++j) {
      float vo = wredV[tid * 4 + j];
      int io = wredI[tid * 4 + j];
      if (vo > v || (vo == v && io < i)) { v = vo; i = io; }
    }
    idxS[tid] = i;
  }
  __syncthreads();

  // ---- update: r' = bf16(r - q) from LDS A -> global state; commit ----
  const int lr = tid >> 3;
  const int token = (lr < 16) ? (tokA + lr) : (tokB + lr - 16);
  const int code = idxS[lr];
  const float* qrow = cbf + (size_t)code * 512;
  uint16_t* arow = As + lr * AST;
  uint16_t* orow = Aout + (size_t)token * 512;
  float s = 0.f;
#pragma unroll
  for (int it = 0; it < 16; ++it) {
    const int d = (tid & 7) * 4 + it * 32;
    float4 q = *(const float4*)(qrow + d);
    uint2 rp = *(uint2*)(arow + d);
    union { uint16_t u[4]; uint2 v; } ri, ro;
    ri.v = rp;
    float r0 = bf2f(ri.u[0]), r1 = bf2f(ri.u[1]);
    float r2 = bf2f(ri.u[2]), r3 = bf2f(ri.u[3]);
    float d0 = q.x - r0, d1 = q.y - r1, d2 = q.z - r2, d3 = q.w - r3;
    s += d0 * d0 + d1 * d1 + d2 * d2 + d3 * d3;
    ro.u[0] = f2bf(r0 - q.x); ro.u[1] = f2bf(r1 - q.y);
    ro.u[2] = f2bf(r2 - q.z); ro.u[3] = f2bf(r3 - q.w);
    *(uint2*)(orow + d) = ro.v;
  }
  cred[tid] = s;
  __syncthreads();
  for (int st = 128; st > 0; st >>= 1) {
    if (tid < st) cred[tid] += cred[tid + st];
    __syncthreads();
  }
  if (tid == 0) cp[blk] = cred[0];
}

// ---------- finalize ----------
__global__ __launch_bounds__(256) void finalize_kernel(
    const float* __restrict__ cp, int ncp, const float* __restrict__ mp, int nmp,
    uint32_t* __restrict__ out) {
  __shared__ double sd[256];
  const int tid = threadIdx.x;
  double s = 0.0, sm = 0.0;
  for (int m = tid; m < ncp; m += 256) s += (double)cp[m];
  for (int m = tid; m < nmp; m += 256) sm += (double)mp[m];
  sd[tid] = s;
  __syncthreads();
  for (int st = 128; st > 0; st >>= 1) {
    if (tid < st) sd[tid] += sd[tid + st];
    __syncthreads();
  }
  double commit_total = sd[0];
  __syncthreads();
  sd[tid] = sm;
  __syncthreads();
  for (int st = 128; st > 0; st >>= 1) {
    if (tid < st) sd[tid] += sd[tid + st];
    __syncthreads();
  }
  if (tid == 0) {
    double commit = commit_total / (16384.0 * 512.0) / 8.0;
    double mse = sd[0] / (16384.0 * 100.0);
    float res = (float)(mse + commit);
    uint32_t fb = __float_as_uint(res);
    uint32_t lsb = (fb >> 16) & 1u;
    uint32_t hb = (fb + 0x7FFFu + lsb) >> 16;
    out[0] = (hb << 16) | hb;  // bf16 low 2B exact; f32 read within 0.4%
  }
}

// host-side threefry for stage keys
inline uint32_t h_rotl(uint32_t x, int r) { return (x << r) | (x >> (32 - r)); }
inline void h_tf2x32(uint32_t k0, uint32_t k1, uint32_t x0, uint32_t x1,
                     uint32_t* o0, uint32_t* o1) {
  const uint32_t k2 = k0 ^ k1 ^ 0x1BD11BDAu;
  const int R[2][4] = {{13, 15, 26, 6}, {17, 29, 16, 24}};
  const uint32_t ks[3] = {k0, k1, k2};
  x0 += k0; x1 += k1;
  for (int g = 0; g < 5; ++g) {
    for (int j = 0; j < 4; ++j) {
      x0 += x1; x1 = h_rotl(x1, R[g & 1][j]); x1 ^= x0;
    }
    x0 += ks[(g + 1) % 3];
    x1 += ks[(g + 2) % 3] + (uint32_t)(g + 1);
  }
  *o0 = x0; *o1 = x1;
}

}  // namespace

extern "C" void kernel_launch(void* const* d_in, const int* in_sizes, int n_in,
                              void* d_out, int out_size, void* d_ws, size_t ws_size,
                              hipStream_t stream) {
  char* ws = (char*)d_ws;
  uint16_t* z     = (uint16_t*)(ws + 0);           // 16,777,216
  uint16_t* h     = (uint16_t*)(ws + 16777216);    //  8,388,608
  uint16_t* rbf   = (uint16_t*)(ws + 25165824);    // 16,777,216 (state / dec_in)
  uint16_t* xbf   = (uint16_t*)(ws + 41943040);    //  4,194,304
  uint16_t* cbh   = (uint16_t*)(ws + 46137344);    //  1,048,576
  float*    cbf   = (float*)   (ws + 47185920);    //  2,097,152
  uint16_t* Wenc1 = (uint16_t*)(ws + 49283072);    //    196,608
  uint16_t* Wenc2 = (uint16_t*)(ws + 49479680);    //    786,432
  uint16_t* Wdec1 = (uint16_t*)(ws + 50266112);    //    786,432
  uint16_t* Wdec2 = (uint16_t*)(ws + 51052544);    //    196,608
  float*    eb1   = (float*)   (ws + 51249152);    //      1,024
  float*    eb2   = (float*)   (ws + 51250176);    //      2,048
  float*    db1   = (float*)   (ws + 51252224);    //      1,024
  float*    db2   = (float*)   (ws + 51253248);    //        512
  float*    csqG  = (float*)   (ws + 51253760);    //      4,096
  float*    cp    = (float*)   (ws + 51257856);    //     16,384 (8*512)
  float*    mp    = (float*)   (ws + 51274240);    //      1,024
  uint32_t* flag  = (uint32_t*)(ws + 51275264);    //          4

  detect_kernel<<<1, 256, 0, stream>>>((const uint32_t*)d_in[0], flag);

  cvt_f32_kernel<<<1, 256, 0, stream>>>(d_in[2], eb1, 256, flag);
  cvt_f32_kernel<<<2, 256, 0, stream>>>(d_in[4], eb2, 512, flag);
  cvt_f32_kernel<<<1, 256, 0, stream>>>(d_in[7], db1, 256, flag);
  cvt_f32_kernel<<<1, 256, 0, stream>>>(d_in[9], db2, 100, flag);
  cvt_f32_kernel<<<2048, 256, 0, stream>>>(d_in[5], cbf, 524288, flag);
  cvt_bf16_kernel<<<2048, 256, 0, stream>>>(d_in[5], cbh, 524288, flag);
  pack_w_kernel<<<(3 * 256 * 128 + 255) / 256, 256, 0, stream>>>(d_in[1], Wenc1, 256, 100, 256, 128, flag);
  pack_w_kernel<<<(3 * 512 * 256 + 255) / 256, 256, 0, stream>>>(d_in[3], Wenc2, 512, 256, 512, 256, flag);
  pack_w_kernel<<<(3 * 256 * 512 + 255) / 256, 256, 0, stream>>>(d_in[6], Wdec1, 256, 512, 256, 512, flag);
  pack_w_kernel<<<(3 * 128 * 256 + 255) / 256, 256, 0, stream>>>(d_in[8], Wdec2, 100, 256, 128, 256, flag);
  pack_x_kernel<<<(kTok * 128) / 256, 256, 0, stream>>>(d_in[0], xbf, flag);
  csq_kernel<<<kK / 4, 256, 0, stream>>>(cbf, csqG);

  conv_mfma_kernel<128, 256, 256, 0><<<256, 256, 0, stream>>>(
      xbf, Wenc1, eb1, h, nullptr, nullptr, flag, nullptr);
  conv_mfma_kernel<256, 512, 512, 0><<<256, 256, 0, stream>>>(
      h, Wenc2, eb2, z, nullptr, nullptr, flag, nullptr);

  for (int i = 0; i < 8; ++i) {
    uint32_t k0, k1;
    h_tf2x32(0u, 42u, 0u, (uint32_t)i, &k0, &k1);  // fold_in(key(42), i)
    vq_stage_kernel<<<512, 256, 0, stream>>>(
        (i == 0) ? z : rbf, rbf, cbh, cbf, csqG, cp + i * 512, k0, k1);
  }

  dec_in_kernel<<<(kTok * kD / 4) / 256, 256, 0, stream>>>(z, rbf);
  conv_mfma_kernel<512, 256, 256, 0><<<256, 256, 0, stream>>>(
      rbf, Wdec1, db1, h, nullptr, nullptr, flag, nullptr);
  conv_mfma_kernel<256, 128, 100, 2><<<256, 256, 0, stream>>>(
      h, Wdec2, db2, nullptr, nullptr, d_in[0], flag, mp);

  finalize_kernel<<<1, 256, 0, stream>>>(cp, 8 * 512, mp, 256, (uint32_t*)d_out);
}

// Round 9
// 867.271 us; speedup vs baseline: 1.0336x; 1.0336x over previous
//
#include <hip/hip_runtime.h>
#include <cstdint>

namespace {

constexpr int kT = 2048;
constexpr int kTok = 16384;
constexpr int kD = 512;
constexpr int kK = 1024;

typedef __attribute__((ext_vector_type(8))) short short8;   // 8 bf16 (4 VGPR)
typedef __attribute__((ext_vector_type(4))) float f32x4;

// ---------- helpers ----------
__device__ __forceinline__ float bf2f(uint16_t u) {
  union { uint32_t i; float f; } c; c.i = ((uint32_t)u) << 16; return c.f;
}
__device__ __forceinline__ uint16_t f2bf(float x) {
  union { float f; uint32_t i; } c; c.f = x;
  uint32_t lsb = (c.i >> 16) & 1u;
  return (uint16_t)((c.i + 0x7FFFu + lsb) >> 16);
}
__device__ __forceinline__ float gelu_f(float v) {
  return 0.5f * v * (1.0f + erff(v * 0.70710678118654752440f));
}
__device__ __forceinline__ uint32_t rotl32(uint32_t x, int r) {
  return (x << r) | (x >> (32 - r));
}

// Threefry-2x32, 20 rounds — bit-exact jax threefry (verified absmax=0 R2-R8)
__device__ __forceinline__ void tf2x32(uint32_t k0, uint32_t k1,
                                       uint32_t x0, uint32_t x1,
                                       uint32_t& o0, uint32_t& o1) {
  const uint32_t k2 = k0 ^ k1 ^ 0x1BD11BDAu;
  x0 += k0; x1 += k1;
#define TF_R(r) { x0 += x1; x1 = rotl32(x1, (r)); x1 ^= x0; }
  TF_R(13) TF_R(15) TF_R(26) TF_R(6)
  x0 += k1; x1 += k2 + 1u;
  TF_R(17) TF_R(29) TF_R(16) TF_R(24)
  x0 += k2; x1 += k0 + 2u;
  TF_R(13) TF_R(15) TF_R(26) TF_R(6)
  x0 += k0; x1 += k1 + 3u;
  TF_R(17) TF_R(29) TF_R(16) TF_R(24)
  x0 += k1; x1 += k2 + 4u;
  TF_R(13) TF_R(15) TF_R(26) TF_R(6)
  x0 += k2; x1 += k0 + 5u;
#undef TF_R
  o0 = x0; o1 = x1;
}

__device__ __forceinline__ float gumbel_bits(uint32_t bits) {
  float f = __uint_as_float((bits >> 9) | 0x3f800000u) - 1.0f;
  const float tiny = 1.17549435e-38f;
  float u = fmaxf(tiny, f + tiny);
  return -__logf(-__logf(u));
}
// gumbel in [-4.4698, 16.6356] by construction -> spread 21.1053; score =
// d*10 + g => codes with d < dmax - 2.11053 can never win. Filter at 2.2.

// ---------- dtype detection (unchanged; passed R2-R8) ----------
__global__ __launch_bounds__(256) void detect_kernel(const uint32_t* __restrict__ w,
                                                     uint32_t* __restrict__ flag) {
  __shared__ int red[256];
  int c = 0;
#pragma unroll
  for (int j = 0; j < 16; ++j) {
    uint32_t v = w[threadIdx.x * 16 + j];
    uint32_t e0 = (v >> 7) & 0xFFu;
    c += (e0 >= 100u && e0 <= 130u) ? 1 : 0;
  }
  red[threadIdx.x] = c;
  __syncthreads();
  for (int st = 128; st > 0; st >>= 1) {
    if (threadIdx.x < st) red[threadIdx.x] += red[threadIdx.x + st];
    __syncthreads();
  }
  if (threadIdx.x == 0) flag[0] = (red[0] > 2048) ? 1u : 0u;  // 1 = bf16
}

__device__ __forceinline__ float load_flag(const void* src, size_t i, uint32_t fl) {
  return fl ? bf2f(((const uint16_t*)src)[i]) : ((const float*)src)[i];
}

__global__ __launch_bounds__(256) void cvt_f32_kernel(const void* __restrict__ src,
                                                      float* __restrict__ dst, int n,
                                                      const uint32_t* __restrict__ flag) {
  int i = blockIdx.x * 256 + threadIdx.x;
  if (i >= n) return;
  dst[i] = load_flag(src, i, flag[0]);
}

__global__ __launch_bounds__(256) void cvt_bf16_kernel(const void* __restrict__ src,
                                                       uint16_t* __restrict__ dst, int n,
                                                       const uint32_t* __restrict__ flag) {
  int i = blockIdx.x * 256 + threadIdx.x;
  if (i >= n) return;
  if (flag[0]) dst[i] = ((const uint16_t*)src)[i];
  else         dst[i] = f2bf(((const float*)src)[i]);
}

// pack conv weights [CO][CI][3] -> bf16 tap-split [3][COP][CIP], zero-padded
__global__ __launch_bounds__(256) void pack_w_kernel(
    const void* __restrict__ src, uint16_t* __restrict__ dst,
    int CO, int CI, int COP, int CIP, const uint32_t* __restrict__ flag) {
  int i = blockIdx.x * 256 + threadIdx.x;
  int n = 3 * COP * CIP;
  if (i >= n) return;
  int tap = i / (COP * CIP);
  int rem = i - tap * COP * CIP;
  int co = rem / CIP, ci = rem - co * CIP;
  uint16_t v = 0;
  if (co < CO && ci < CI) {
    float f = load_flag(src, ((size_t)co * CI + ci) * 3 + tap, flag[0]);
    v = f2bf(f);
  }
  dst[i] = v;
}

// pack x [16384][100] (flag dtype) -> bf16 [16384][128] zero-padded
__global__ __launch_bounds__(256) void pack_x_kernel(const void* __restrict__ src,
                                                     uint16_t* __restrict__ dst,
                                                     const uint32_t* __restrict__ flag) {
  int i = blockIdx.x * 256 + threadIdx.x;  // over 16384*128
  int tok = i >> 7, ci = i & 127;
  uint16_t v = 0;
  if (ci < 100) {
    float f = load_flag(src, (size_t)tok * 100 + ci, flag[0]);
    v = f2bf(f);
  }
  dst[i] = v;
}

// dec_in (in place): r <- bf16(z - r), over 16384*512 elems, x4 vectorized
__global__ __launch_bounds__(256) void dec_in_kernel(const uint16_t* __restrict__ z,
                                                     uint16_t* __restrict__ r) {
  int i = blockIdx.x * 256 + threadIdx.x;
  uint2 zp = ((const uint2*)z)[i];
  uint2 rp = ((uint2*)r)[i];
  union { uint16_t u[4]; uint2 v; } zi, ri, out;
  zi.v = zp; ri.v = rp;
  out.u[0] = f2bf(bf2f(zi.u[0]) - bf2f(ri.u[0]));
  out.u[1] = f2bf(bf2f(zi.u[1]) - bf2f(ri.u[1]));
  out.u[2] = f2bf(bf2f(zi.u[2]) - bf2f(ri.u[2]));
  out.u[3] = f2bf(bf2f(zi.u[3]) - bf2f(ri.u[3]));
  ((uint2*)r)[i] = out.v;
}

// ---------- codebook squared norms ----------
__global__ __launch_bounds__(256) void csq_kernel(const float* __restrict__ cb,
                                                  float* __restrict__ c_sq) {
  const int lane = threadIdx.x & 63;
  const int k = blockIdx.x * 4 + (threadIdx.x >> 6);
  const float* row = cb + (size_t)k * kD;
  float s = 0.f;
#pragma unroll
  for (int j = 0; j < 8; ++j) {
    float v = row[lane + 64 * j];
    s = fmaf(v, v, s);
  }
  for (int off = 32; off > 0; off >>= 1) s += __shfl_down(s, off, 64);
  if (lane == 0) c_sq[k] = s;
}

// ---------- MFMA conv (+GELU), verified R4-R8 (absmax 0.0), unchanged ----------
template <int CIP, int COP, int CO_REAL, int OMODE>
__global__ __launch_bounds__(256) void conv_mfma_kernel(
    const uint16_t* __restrict__ A, const uint16_t* __restrict__ W,
    const float* __restrict__ bias, uint16_t* __restrict__ outb,
    float* __restrict__ outf, const void* __restrict__ xraw,
    const uint32_t* __restrict__ flag, float* __restrict__ partial) {
  constexpr int AST = CIP + 8;
  __shared__ uint16_t As[66 * AST];
  __shared__ uint16_t Bs[128 * 72];
  __shared__ float red[256];

  const int tid = threadIdx.x;
  const int w = tid >> 6;
  const int lane = tid & 63;
  const int quad = lane >> 4;
  const int col = lane & 15;
  const int tok0 = blockIdx.x * 64;
  const int t0 = tok0 & (kT - 1);

  constexpr int AV = 66 * (CIP / 8);
  for (int m = tid; m < AV; m += 256) {
    int r = m / (CIP / 8), c8 = m % (CIP / 8);
    bool valid = !((r == 0 && t0 == 0) || (r == 65 && t0 == kT - 64));
    uint4 v = {0, 0, 0, 0};
    if (valid) v = *(const uint4*)(A + (size_t)(tok0 - 1 + r) * CIP + c8 * 8);
    *(uint4*)(As + r * AST + c8 * 8) = v;
  }

  float part = 0.f;
#pragma unroll 1
  for (int chunk = 0; chunk < COP / 128; ++chunk) {
    f32x4 acc[4][2];
#pragma unroll
    for (int mt = 0; mt < 4; ++mt)
#pragma unroll
      for (int nt = 0; nt < 2; ++nt) acc[mt][nt] = (f32x4){0.f, 0.f, 0.f, 0.f};

#pragma unroll 1
    for (int tap = 0; tap < 3; ++tap) {
#pragma unroll 1
      for (int kt = 0; kt < CIP / 64; ++kt) {
        __syncthreads();
#pragma unroll
        for (int it = 0; it < 4; ++it) {
          int m = it * 256 + tid;
          int rr = m >> 3, c8 = m & 7;
          *(uint4*)(Bs + rr * 72 + c8 * 8) =
              *(const uint4*)(W + ((size_t)tap * COP + chunk * 128 + rr) * CIP + kt * 64 + c8 * 8);
        }
        __syncthreads();
#pragma unroll
        for (int kk = 0; kk < 2; ++kk) {
          short8 bf0 = *(const short8*)(Bs + (w * 32 + col) * 72 + kk * 32 + quad * 8);
          short8 bf1 = *(const short8*)(Bs + (w * 32 + 16 + col) * 72 + kk * 32 + quad * 8);
#pragma unroll
          for (int mt = 0; mt < 4; ++mt) {
            short8 af = *(const short8*)(As + (mt * 16 + col + tap) * AST + kt * 64 + kk * 32 + quad * 8);
            acc[mt][0] = __builtin_amdgcn_mfma_f32_16x16x32_bf16(af, bf0, acc[mt][0], 0, 0, 0);
            acc[mt][1] = __builtin_amdgcn_mfma_f32_16x16x32_bf16(af, bf1, acc[mt][1], 0, 0, 0);
          }
        }
      }
    }
#pragma unroll
    for (int nt = 0; nt < 2; ++nt) {
      const int co = chunk * 128 + w * 32 + nt * 16 + col;
      const float bv = (OMODE == 2 && co >= CO_REAL) ? 0.f : bias[co];
#pragma unroll
      for (int mt = 0; mt < 4; ++mt) {
#pragma unroll
        for (int rg = 0; rg < 4; ++rg) {
          const int token = tok0 + mt * 16 + quad * 4 + rg;
          float g = gelu_f(acc[mt][nt][rg] + bv);
          if constexpr (OMODE == 0) {
            outb[(size_t)token * CO_REAL + co] = f2bf(g);
          } else if constexpr (OMODE == 1) {
            outf[(size_t)token * CO_REAL + co] = g;
            outb[(size_t)token * CO_REAL + co] = f2bf(g);
          } else {
            if (co < CO_REAL) {
              float xv = load_flag(xraw, (size_t)token * CO_REAL + co, flag[0]);
              float d = xv - g;
              part += d * d;
            }
          }
        }
      }
    }
  }
  if constexpr (OMODE == 2) {
    red[tid] = part;
    __syncthreads();
    for (int st = 128; st > 0; st >>= 1) {
      if (tid < st) red[tid] += red[tid + st];
      __syncthreads();
    }
    if (tid == 0) partial[blockIdx.x] = red[0];
  }
}

// ---------- VQ stage: 8-wave blocks, barrier-free GEMM, 4 waves/SIMD ----------
// 512 blocks x 512 thr (8 waves), 32 tokens/block (16+16 paired halves).
// Each wave owns 128 codes (acc = 64 VGPRs); B-frags direct from L2-resident
// codebook, depth-1 ring over half-K steps (bf[2][4] = 32 VGPRs).
// __launch_bounds__(512,4) caps VGPR at 128 -> 2 blocks/CU = 4 waves/SIMD:
// L2 latency is hidden by TLP (R7/R8 showed 2 waves/SIMD + reg-ring cannot
// hide it; compiler refuses deep in-register prefetch). Single pass over all
// codes -> true global dmax filter (margin 2.2, selection-exact).
__global__ __launch_bounds__(512, 4) void vq_stage_kernel(
    const uint16_t* __restrict__ Ain, uint16_t* __restrict__ Aout,
    const uint16_t* __restrict__ cbh, const float* __restrict__ cbf,
    const float* __restrict__ csqG, float* __restrict__ cp,
    uint32_t key0, uint32_t key1) {
  constexpr int AST = 528;
  __shared__ uint16_t As[32 * AST];   // 33,792 B
  __shared__ float csqS[1024];        // 4 KB
  __shared__ float dmaxW[32 * 8];
  __shared__ float thrS[32];
  __shared__ float wredV[32 * 8];
  __shared__ int   wredI[32 * 8];
  __shared__ int   idxS[32];
  __shared__ float cred[512];

  const int tid = threadIdx.x;
  const int w = tid >> 6;        // 0..7
  const int lane = tid & 63;
  const int quad = lane >> 4;
  const int col = lane & 15;
  const int blk = blockIdx.x;
  const int tokA = blk * 16;
  const int tokB = 8192 + blk * 16;

  if (tid < 256) ((f32x4*)csqS)[tid] = ((const f32x4*)csqG)[tid];

  // stage A: 32 rows x 512 bf16 (rows 0-15 first half, 16-31 second half)
#pragma unroll
  for (int it = 0; it < 4; ++it) {
    int m = it * 512 + tid;
    int r = m >> 6, c8 = m & 63;
    int token = (r < 16) ? (tokA + r) : (tokB + r - 16);
    *(uint4*)(As + r * AST + c8 * 8) =
        *(const uint4*)(Ain + (size_t)token * 512 + c8 * 8);
  }
  __syncthreads();

  f32x4 acc[2][8];  // [mt][nt] — wave's 128 codes
#pragma unroll
  for (int mt = 0; mt < 2; ++mt)
#pragma unroll
    for (int nt = 0; nt < 8; ++nt) acc[mt][nt] = (f32x4){0.f, 0.f, 0.f, 0.f};

  // ---- barrier-free GEMM: 32 half-steps (ks = s>>1, nt-group = s&1) ----
  const uint16_t* bb = cbh + (size_t)(w * 128 + col) * 512 + quad * 8;
  short8 bf[2][4];
#pragma unroll
  for (int j = 0; j < 4; ++j) bf[0][j] = *(const short8*)(bb + j * 8192);

  short8 a0, a1;
#pragma unroll
  for (int s = 0; s < 32; ++s) {
    if (s < 31) {
      const int sn = s + 1;
      const int ksn = sn >> 1, gn = sn & 1;
#pragma unroll
      for (int j = 0; j < 4; ++j)
        bf[sn & 1][j] = *(const short8*)(bb + (size_t)(gn * 4 + j) * 8192 + ksn * 32);
    }
    const int ks = s >> 1, g = s & 1;
    if (g == 0) {
      const int koff = ks * 32 + quad * 8;
      a0 = *(const short8*)(As + col * AST + koff);
      a1 = *(const short8*)(As + (col + 16) * AST + koff);
    }
#pragma unroll
    for (int j = 0; j < 4; ++j) {
      const int nt = g * 4 + j;
      acc[0][nt] = __builtin_amdgcn_mfma_f32_16x16x32_bf16(a0, bf[s & 1][j], acc[0][nt], 0, 0, 0);
      acc[1][nt] = __builtin_amdgcn_mfma_f32_16x16x32_bf16(a1, bf[s & 1][j], acc[1][nt], 0, 0, 0);
    }
  }

  // ---- per-token dmax: regs -> 16-lane shfl -> LDS over 8 waves ----
  float dmx[2][4];
#pragma unroll
  for (int mt = 0; mt < 2; ++mt)
#pragma unroll
    for (int rg = 0; rg < 4; ++rg) dmx[mt][rg] = -INFINITY;
#pragma unroll
  for (int nt = 0; nt < 8; ++nt) {
    const int code = w * 128 + nt * 16 + col;
    const float csqv = csqS[code];
#pragma unroll
    for (int rg = 0; rg < 4; ++rg) {
      dmx[0][rg] = fmaxf(dmx[0][rg], acc[0][nt][rg] * 2.f - csqv);
      dmx[1][rg] = fmaxf(dmx[1][rg], acc[1][nt][rg] * 2.f - csqv);
    }
  }
#pragma unroll
  for (int mt = 0; mt < 2; ++mt)
#pragma unroll
    for (int rg = 0; rg < 4; ++rg) {
      float v = dmx[mt][rg];
#pragma unroll
      for (int m = 8; m >= 1; m >>= 1) v = fmaxf(v, __shfl_xor(v, m));
      if (col == 0) dmaxW[(mt * 16 + quad * 4 + rg) * 8 + w] = v;
    }
  __syncthreads();
  if (tid < 32) {
    float v = dmaxW[tid * 8];
#pragma unroll
    for (int j = 1; j < 8; ++j) v = fmaxf(v, dmaxW[tid * 8 + j]);
    thrS[tid] = v - 2.2f;
  }
  __syncthreads();

  float thr0[4], thr1[4];
#pragma unroll
  for (int rg = 0; rg < 4; ++rg) {
    thr0[rg] = thrS[quad * 4 + rg];
    thr1[rg] = thrS[16 + quad * 4 + rg];
  }

  // ---- filtered gumbel + per-lane argmax (codes ascending per lane) ----
  float bestV[2][4];
  int bestI[2][4];
#pragma unroll
  for (int mt = 0; mt < 2; ++mt)
#pragma unroll
    for (int rg = 0; rg < 4; ++rg) { bestV[mt][rg] = -INFINITY; bestI[mt][rg] = 0; }

#pragma unroll
  for (int nt = 0; nt < 8; ++nt) {
    const int code = w * 128 + nt * 16 + col;
    const float csqv = csqS[code];
#pragma unroll
    for (int rg = 0; rg < 4; ++rg) {
      float d0 = acc[0][nt][rg] * 2.f - csqv;
      float d1 = acc[1][nt][rg] * 2.f - csqv;
      bool c0 = d0 >= thr0[rg];
      bool c1 = d1 >= thr1[rg];
      if (c0 || c1) {
        const uint32_t n = (uint32_t)(tokA + quad * 4 + rg) * 1024u + (uint32_t)code;
        uint32_t o0, o1;
        tf2x32(key0, key1, n, n + 8388608u, o0, o1);
        if (c0) {
          float s0 = d0 * 10.f + gumbel_bits(o0);
          if (s0 > bestV[0][rg]) { bestV[0][rg] = s0; bestI[0][rg] = code; }
        }
        if (c1) {
          float s1 = d1 * 10.f + gumbel_bits(o1);
          if (s1 > bestV[1][rg]) { bestV[1][rg] = s1; bestI[1][rg] = code; }
        }
      }
    }
  }

  // 16-lane shfl argmax (tie: smaller code), then cross-wave via LDS
#pragma unroll
  for (int mt = 0; mt < 2; ++mt)
#pragma unroll
    for (int rg = 0; rg < 4; ++rg) {
      float v = bestV[mt][rg];
      int i = bestI[mt][rg];
#pragma unroll
      for (int m = 8; m >= 1; m >>= 1) {
        float vo = __shfl_xor(v, m);
        int io = __shfl_xor(i, m);
        if (vo > v || (vo == v && io < i)) { v = vo; i = io; }
      }
      if (col == 0) {
        const int row = mt * 16 + quad * 4 + rg;
        wredV[row * 8 + w] = v;
        wredI[row * 8 + w] = i;
      }
    }
  __syncthreads();
  if (tid < 32) {
    float v = wredV[tid * 8];
    int i = wredI[tid * 8];
#pragma unroll
    for (int j = 1; j < 8; ++j) {
      float vo = wredV[tid * 8 + j];
      int io = wredI[tid * 8 + j];
      if (vo > v || (vo == v && io < i)) { v = vo; i = io; }
    }
    idxS[tid] = i;
  }
  __syncthreads();

  // ---- update: r' = bf16(r - q) from LDS A -> global state; commit ----
  const int lr = tid >> 4;                 // 32 rows, 16 thr/row
  const int token = (lr < 16) ? (tokA + lr) : (tokB + lr - 16);
  const int code = idxS[lr];
  const float* qrow = cbf + (size_t)code * 512;
  uint16_t* arow = As + lr * AST;
  uint16_t* orow = Aout + (size_t)token * 512;
  float s = 0.f;
#pragma unroll
  for (int it = 0; it < 8; ++it) {
    const int d = (tid & 15) * 4 + it * 64;
    float4 q = *(const float4*)(qrow + d);
    uint2 rp = *(uint2*)(arow + d);
    union { uint16_t u[4]; uint2 v; } ri, ro;
    ri.v = rp;
    float r0 = bf2f(ri.u[0]), r1 = bf2f(ri.u[1]);
    float r2 = bf2f(ri.u[2]), r3 = bf2f(ri.u[3]);
    float d0 = q.x - r0, d1 = q.y - r1, d2 = q.z - r2, d3 = q.w - r3;
    s += d0 * d0 + d1 * d1 + d2 * d2 + d3 * d3;
    ro.u[0] = f2bf(r0 - q.x); ro.u[1] = f2bf(r1 - q.y);
    ro.u[2] = f2bf(r2 - q.z); ro.u[3] = f2bf(r3 - q.w);
    *(uint2*)(orow + d) = ro.v;
  }
  cred[tid] = s;
  __syncthreads();
  for (int st = 256; st > 0; st >>= 1) {
    if (tid < st) cred[tid] += cred[tid + st];
    __syncthreads();
  }
  if (tid == 0) cp[blk] = cred[0];
}

// ---------- finalize ----------
__global__ __launch_bounds__(256) void finalize_kernel(
    const float* __restrict__ cp, int ncp, const float* __restrict__ mp, int nmp,
    uint32_t* __restrict__ out) {
  __shared__ double sd[256];
  const int tid = threadIdx.x;
  double s = 0.0, sm = 0.0;
  for (int m = tid; m < ncp; m += 256) s += (double)cp[m];
  for (int m = tid; m < nmp; m += 256) sm += (double)mp[m];
  sd[tid] = s;
  __syncthreads();
  for (int st = 128; st > 0; st >>= 1) {
    if (tid < st) sd[tid] += sd[tid + st];
    __syncthreads();
  }
  double commit_total = sd[0];
  __syncthreads();
  sd[tid] = sm;
  __syncthreads();
  for (int st = 128; st > 0; st >>= 1) {
    if (tid < st) sd[tid] += sd[tid + st];
    __syncthreads();
  }
  if (tid == 0) {
    double commit = commit_total / (16384.0 * 512.0) / 8.0;
    double mse = sd[0] / (16384.0 * 100.0);
    float res = (float)(mse + commit);
    uint32_t fb = __float_as_uint(res);
    uint32_t lsb = (fb >> 16) & 1u;
    uint32_t hb = (fb + 0x7FFFu + lsb) >> 16;
    out[0] = (hb << 16) | hb;  // bf16 low 2B exact; f32 read within 0.4%
  }
}

// host-side threefry for stage keys
inline uint32_t h_rotl(uint32_t x, int r) { return (x << r) | (x >> (32 - r)); }
inline void h_tf2x32(uint32_t k0, uint32_t k1, uint32_t x0, uint32_t x1,
                     uint32_t* o0, uint32_t* o1) {
  const uint32_t k2 = k0 ^ k1 ^ 0x1BD11BDAu;
  const int R[2][4] = {{13, 15, 26, 6}, {17, 29, 16, 24}};
  const uint32_t ks[3] = {k0, k1, k2};
  x0 += k0; x1 += k1;
  for (int g = 0; g < 5; ++g) {
    for (int j = 0; j < 4; ++j) {
      x0 += x1; x1 = h_rotl(x1, R[g & 1][j]); x1 ^= x0;
    }
    x0 += ks[(g + 1) % 3];
    x1 += ks[(g + 2) % 3] + (uint32_t)(g + 1);
  }
  *o0 = x0; *o1 = x1;
}

}  // namespace

extern "C" void kernel_launch(void* const* d_in, const int* in_sizes, int n_in,
                              void* d_out, int out_size, void* d_ws, size_t ws_size,
                              hipStream_t stream) {
  char* ws = (char*)d_ws;
  uint16_t* z     = (uint16_t*)(ws + 0);           // 16,777,216
  uint16_t* h     = (uint16_t*)(ws + 16777216);    //  8,388,608
  uint16_t* rbf   = (uint16_t*)(ws + 25165824);    // 16,777,216 (state / dec_in)
  uint16_t* xbf   = (uint16_t*)(ws + 41943040);    //  4,194,304
  uint16_t* cbh   = (uint16_t*)(ws + 46137344);    //  1,048,576
  float*    cbf   = (float*)   (ws + 47185920);    //  2,097,152
  uint16_t* Wenc1 = (uint16_t*)(ws + 49283072);    //    196,608
  uint16_t* Wenc2 = (uint16_t*)(ws + 49479680);    //    786,432
  uint16_t* Wdec1 = (uint16_t*)(ws + 50266112);    //    786,432
  uint16_t* Wdec2 = (uint16_t*)(ws + 51052544);    //    196,608
  float*    eb1   = (float*)   (ws + 51249152);    //      1,024
  float*    eb2   = (float*)   (ws + 51250176);    //      2,048
  float*    db1   = (float*)   (ws + 51252224);    //      1,024
  float*    db2   = (float*)   (ws + 51253248);    //        512
  float*    csqG  = (float*)   (ws + 51253760);    //      4,096
  float*    cp    = (float*)   (ws + 51257856);    //     16,384 (8*512)
  float*    mp    = (float*)   (ws + 51274240);    //      1,024
  uint32_t* flag  = (uint32_t*)(ws + 51275264);    //          4

  detect_kernel<<<1, 256, 0, stream>>>((const uint32_t*)d_in[0], flag);

  cvt_f32_kernel<<<1, 256, 0, stream>>>(d_in[2], eb1, 256, flag);
  cvt_f32_kernel<<<2, 256, 0, stream>>>(d_in[4], eb2, 512, flag);
  cvt_f32_kernel<<<1, 256, 0, stream>>>(d_in[7], db1, 256, flag);
  cvt_f32_kernel<<<1, 256, 0, stream>>>(d_in[9], db2, 100, flag);
  cvt_f32_kernel<<<2048, 256, 0, stream>>>(d_in[5], cbf, 524288, flag);
  cvt_bf16_kernel<<<2048, 256, 0, stream>>>(d_in[5], cbh, 524288, flag);
  pack_w_kernel<<<(3 * 256 * 128 + 255) / 256, 256, 0, stream>>>(d_in[1], Wenc1, 256, 100, 256, 128, flag);
  pack_w_kernel<<<(3 * 512 * 256 + 255) / 256, 256, 0, stream>>>(d_in[3], Wenc2, 512, 256, 512, 256, flag);
  pack_w_kernel<<<(3 * 256 * 512 + 255) / 256, 256, 0, stream>>>(d_in[6], Wdec1, 256, 512, 256, 512, flag);
  pack_w_kernel<<<(3 * 128 * 256 + 255) / 256, 256, 0, stream>>>(d_in[8], Wdec2, 100, 256, 128, 256, flag);
  pack_x_kernel<<<(kTok * 128) / 256, 256, 0, stream>>>(d_in[0], xbf, flag);
  csq_kernel<<<kK / 4, 256, 0, stream>>>(cbf, csqG);

  conv_mfma_kernel<128, 256, 256, 0><<<256, 256, 0, stream>>>(
      xbf, Wenc1, eb1, h, nullptr, nullptr, flag, nullptr);
  conv_mfma_kernel<256, 512, 512, 0><<<256, 256, 0, stream>>>(
      h, Wenc2, eb2, z, nullptr, nullptr, flag, nullptr);

  for (int i = 0; i < 8; ++i) {
    uint32_t k0, k1;
    h_tf2x32(0u, 42u, 0u, (uint32_t)i, &k0, &k1);  // fold_in(key(42), i)
    vq_stage_kernel<<<512, 512, 0, stream>>>(
        (i == 0) ? z : rbf, rbf, cbh, cbf, csqG, cp + i * 512, k0, k1);
  }

  dec_in_kernel<<<(kTok * kD / 4) / 256, 256, 0, stream>>>(z, rbf);
  conv_mfma_kernel<512, 256, 256, 0><<<256, 256, 0, stream>>>(
      rbf, Wdec1, db1, h, nullptr, nullptr, flag, nullptr);
  conv_mfma_kernel<256, 128, 100, 2><<<256, 256, 0, stream>>>(
      h, Wdec2, db2, nullptr, nullptr, d_in[0], flag, mp);

  finalize_kernel<<<1, 256, 0, stream>>>(cp, 8 * 512, mp, 256, (uint32_t*)d_out);
}

// Round 10
// 695.981 us; speedup vs baseline: 1.2879x; 1.2461x over previous
//
#include <hip/hip_runtime.h>
#include <cstdint>

namespace {

constexpr int kT = 2048;
constexpr int kTok = 16384;
constexpr int kD = 512;
constexpr int kK = 1024;

typedef __attribute__((ext_vector_type(8))) short short8;   // 8 bf16 (4 VGPR)
typedef __attribute__((ext_vector_type(4))) float f32x4;

// ---------- helpers ----------
__device__ __forceinline__ float bf2f(uint16_t u) {
  union { uint32_t i; float f; } c; c.i = ((uint32_t)u) << 16; return c.f;
}
__device__ __forceinline__ uint16_t f2bf(float x) {
  union { float f; uint32_t i; } c; c.f = x;
  uint32_t lsb = (c.i >> 16) & 1u;
  return (uint16_t)((c.i + 0x7FFFu + lsb) >> 16);
}
__device__ __forceinline__ float gelu_f(float v) {
  return 0.5f * v * (1.0f + erff(v * 0.70710678118654752440f));
}
__device__ __forceinline__ uint32_t rotl32(uint32_t x, int r) {
  return (x << r) | (x >> (32 - r));
}

// Threefry-2x32, 20 rounds — bit-exact jax threefry (verified absmax=0 R2-R9)
__device__ __forceinline__ void tf2x32(uint32_t k0, uint32_t k1,
                                       uint32_t x0, uint32_t x1,
                                       uint32_t& o0, uint32_t& o1) {
  const uint32_t k2 = k0 ^ k1 ^ 0x1BD11BDAu;
  x0 += k0; x1 += k1;
#define TF_R(r) { x0 += x1; x1 = rotl32(x1, (r)); x1 ^= x0; }
  TF_R(13) TF_R(15) TF_R(26) TF_R(6)
  x0 += k1; x1 += k2 + 1u;
  TF_R(17) TF_R(29) TF_R(16) TF_R(24)
  x0 += k2; x1 += k0 + 2u;
  TF_R(13) TF_R(15) TF_R(26) TF_R(6)
  x0 += k0; x1 += k1 + 3u;
  TF_R(17) TF_R(29) TF_R(16) TF_R(24)
  x0 += k1; x1 += k2 + 4u;
  TF_R(13) TF_R(15) TF_R(26) TF_R(6)
  x0 += k2; x1 += k0 + 5u;
#undef TF_R
  o0 = x0; o1 = x1;
}

__device__ __forceinline__ float gumbel_bits(uint32_t bits) {
  float f = __uint_as_float((bits >> 9) | 0x3f800000u) - 1.0f;
  const float tiny = 1.17549435e-38f;
  float u = fmaxf(tiny, f + tiny);
  return -__logf(-__logf(u));
}
// gumbel in [-4.4698, 16.6356] by construction -> spread 21.1053; score =
// d*10 + g => codes with d < dmax - 2.11053 can never win. Filter at 2.2.

// ---------- dtype detection (unchanged; passed R2-R9) ----------
__global__ __launch_bounds__(256) void detect_kernel(const uint32_t* __restrict__ w,
                                                     uint32_t* __restrict__ flag) {
  __shared__ int red[256];
  int c = 0;
#pragma unroll
  for (int j = 0; j < 16; ++j) {
    uint32_t v = w[threadIdx.x * 16 + j];
    uint32_t e0 = (v >> 7) & 0xFFu;
    c += (e0 >= 100u && e0 <= 130u) ? 1 : 0;
  }
  red[threadIdx.x] = c;
  __syncthreads();
  for (int st = 128; st > 0; st >>= 1) {
    if (threadIdx.x < st) red[threadIdx.x] += red[threadIdx.x + st];
    __syncthreads();
  }
  if (threadIdx.x == 0) flag[0] = (red[0] > 2048) ? 1u : 0u;  // 1 = bf16
}

__device__ __forceinline__ float load_flag(const void* src, size_t i, uint32_t fl) {
  return fl ? bf2f(((const uint16_t*)src)[i]) : ((const float*)src)[i];
}

__global__ __launch_bounds__(256) void cvt_f32_kernel(const void* __restrict__ src,
                                                      float* __restrict__ dst, int n,
                                                      const uint32_t* __restrict__ flag) {
  int i = blockIdx.x * 256 + threadIdx.x;
  if (i >= n) return;
  dst[i] = load_flag(src, i, flag[0]);
}

__global__ __launch_bounds__(256) void cvt_bf16_kernel(const void* __restrict__ src,
                                                       uint16_t* __restrict__ dst, int n,
                                                       const uint32_t* __restrict__ flag) {
  int i = blockIdx.x * 256 + threadIdx.x;
  if (i >= n) return;
  if (flag[0]) dst[i] = ((const uint16_t*)src)[i];
  else         dst[i] = f2bf(((const float*)src)[i]);
}

// pack conv weights [CO][CI][3] -> bf16 tap-split [3][COP][CIP], zero-padded
__global__ __launch_bounds__(256) void pack_w_kernel(
    const void* __restrict__ src, uint16_t* __restrict__ dst,
    int CO, int CI, int COP, int CIP, const uint32_t* __restrict__ flag) {
  int i = blockIdx.x * 256 + threadIdx.x;
  int n = 3 * COP * CIP;
  if (i >= n) return;
  int tap = i / (COP * CIP);
  int rem = i - tap * COP * CIP;
  int co = rem / CIP, ci = rem - co * CIP;
  uint16_t v = 0;
  if (co < CO && ci < CI) {
    float f = load_flag(src, ((size_t)co * CI + ci) * 3 + tap, flag[0]);
    v = f2bf(f);
  }
  dst[i] = v;
}

// pack x [16384][100] (flag dtype) -> bf16 [16384][128] zero-padded
__global__ __launch_bounds__(256) void pack_x_kernel(const void* __restrict__ src,
                                                     uint16_t* __restrict__ dst,
                                                     const uint32_t* __restrict__ flag) {
  int i = blockIdx.x * 256 + threadIdx.x;  // over 16384*128
  int tok = i >> 7, ci = i & 127;
  uint16_t v = 0;
  if (ci < 100) {
    float f = load_flag(src, (size_t)tok * 100 + ci, flag[0]);
    v = f2bf(f);
  }
  dst[i] = v;
}

// dec_in (in place): r <- bf16(z - r), over 16384*512 elems, x4 vectorized
__global__ __launch_bounds__(256) void dec_in_kernel(const uint16_t* __restrict__ z,
                                                     uint16_t* __restrict__ r) {
  int i = blockIdx.x * 256 + threadIdx.x;
  uint2 zp = ((const uint2*)z)[i];
  uint2 rp = ((uint2*)r)[i];
  union { uint16_t u[4]; uint2 v; } zi, ri, out;
  zi.v = zp; ri.v = rp;
  out.u[0] = f2bf(bf2f(zi.u[0]) - bf2f(ri.u[0]));
  out.u[1] = f2bf(bf2f(zi.u[1]) - bf2f(ri.u[1]));
  out.u[2] = f2bf(bf2f(zi.u[2]) - bf2f(ri.u[2]));
  out.u[3] = f2bf(bf2f(zi.u[3]) - bf2f(ri.u[3]));
  ((uint2*)r)[i] = out.v;
}

// ---------- codebook squared norms ----------
__global__ __launch_bounds__(256) void csq_kernel(const float* __restrict__ cb,
                                                  float* __restrict__ c_sq) {
  const int lane = threadIdx.x & 63;
  const int k = blockIdx.x * 4 + (threadIdx.x >> 6);
  const float* row = cb + (size_t)k * kD;
  float s = 0.f;
#pragma unroll
  for (int j = 0; j < 8; ++j) {
    float v = row[lane + 64 * j];
    s = fmaf(v, v, s);
  }
  for (int off = 32; off > 0; off >>= 1) s += __shfl_down(s, off, 64);
  if (lane == 0) c_sq[k] = s;
}

// ---------- MFMA conv (+GELU), verified R4-R9 (absmax 0.0), unchanged ----------
template <int CIP, int COP, int CO_REAL, int OMODE>
__global__ __launch_bounds__(256) void conv_mfma_kernel(
    const uint16_t* __restrict__ A, const uint16_t* __restrict__ W,
    const float* __restrict__ bias, uint16_t* __restrict__ outb,
    float* __restrict__ outf, const void* __restrict__ xraw,
    const uint32_t* __restrict__ flag, float* __restrict__ partial) {
  constexpr int AST = CIP + 8;
  __shared__ uint16_t As[66 * AST];
  __shared__ uint16_t Bs[128 * 72];
  __shared__ float red[256];

  const int tid = threadIdx.x;
  const int w = tid >> 6;
  const int lane = tid & 63;
  const int quad = lane >> 4;
  const int col = lane & 15;
  const int tok0 = blockIdx.x * 64;
  const int t0 = tok0 & (kT - 1);

  constexpr int AV = 66 * (CIP / 8);
  for (int m = tid; m < AV; m += 256) {
    int r = m / (CIP / 8), c8 = m % (CIP / 8);
    bool valid = !((r == 0 && t0 == 0) || (r == 65 && t0 == kT - 64));
    uint4 v = {0, 0, 0, 0};
    if (valid) v = *(const uint4*)(A + (size_t)(tok0 - 1 + r) * CIP + c8 * 8);
    *(uint4*)(As + r * AST + c8 * 8) = v;
  }

  float part = 0.f;
#pragma unroll 1
  for (int chunk = 0; chunk < COP / 128; ++chunk) {
    f32x4 acc[4][2];
#pragma unroll
    for (int mt = 0; mt < 4; ++mt)
#pragma unroll
      for (int nt = 0; nt < 2; ++nt) acc[mt][nt] = (f32x4){0.f, 0.f, 0.f, 0.f};

#pragma unroll 1
    for (int tap = 0; tap < 3; ++tap) {
#pragma unroll 1
      for (int kt = 0; kt < CIP / 64; ++kt) {
        __syncthreads();
#pragma unroll
        for (int it = 0; it < 4; ++it) {
          int m = it * 256 + tid;
          int rr = m >> 3, c8 = m & 7;
          *(uint4*)(Bs + rr * 72 + c8 * 8) =
              *(const uint4*)(W + ((size_t)tap * COP + chunk * 128 + rr) * CIP + kt * 64 + c8 * 8);
        }
        __syncthreads();
#pragma unroll
        for (int kk = 0; kk < 2; ++kk) {
          short8 bf0 = *(const short8*)(Bs + (w * 32 + col) * 72 + kk * 32 + quad * 8);
          short8 bf1 = *(const short8*)(Bs + (w * 32 + 16 + col) * 72 + kk * 32 + quad * 8);
#pragma unroll
          for (int mt = 0; mt < 4; ++mt) {
            short8 af = *(const short8*)(As + (mt * 16 + col + tap) * AST + kt * 64 + kk * 32 + quad * 8);
            acc[mt][0] = __builtin_amdgcn_mfma_f32_16x16x32_bf16(af, bf0, acc[mt][0], 0, 0, 0);
            acc[mt][1] = __builtin_amdgcn_mfma_f32_16x16x32_bf16(af, bf1, acc[mt][1], 0, 0, 0);
          }
        }
      }
    }
#pragma unroll
    for (int nt = 0; nt < 2; ++nt) {
      const int co = chunk * 128 + w * 32 + nt * 16 + col;
      const float bv = (OMODE == 2 && co >= CO_REAL) ? 0.f : bias[co];
#pragma unroll
      for (int mt = 0; mt < 4; ++mt) {
#pragma unroll
        for (int rg = 0; rg < 4; ++rg) {
          const int token = tok0 + mt * 16 + quad * 4 + rg;
          float g = gelu_f(acc[mt][nt][rg] + bv);
          if constexpr (OMODE == 0) {
            outb[(size_t)token * CO_REAL + co] = f2bf(g);
          } else if constexpr (OMODE == 1) {
            outf[(size_t)token * CO_REAL + co] = g;
            outb[(size_t)token * CO_REAL + co] = f2bf(g);
          } else {
            if (co < CO_REAL) {
              float xv = load_flag(xraw, (size_t)token * CO_REAL + co, flag[0]);
              float d = xv - g;
              part += d * d;
            }
          }
        }
      }
    }
  }
  if constexpr (OMODE == 2) {
    red[tid] = part;
    __syncthreads();
    for (int st = 128; st > 0; st >>= 1) {
      if (tid < st) red[tid] += red[tid + st];
      __syncthreads();
    }
    if (tid == 0) partial[blockIdx.x] = red[0];
  }
}

// ---------- VQ stage: M=64 tokens/block, 16 waves, single pass ----------
// 256 blocks x 1024 thr (16 waves = 4 waves/SIMD, 1 block/CU).
// Rows 0-31 = tokens [blk*32,+32), rows 32-63 = [8192+blk*32,+32) (threefry
// n/n+2^23 pairing: row r pairs r+32 -> acc[mh] with acc[mh+2]).
// Each wave owns 64 codes (acc = 4mt x 4nt f32x4 = 64 AGPRs); B-frags direct
// from L2 codebook, depth-2 ring. M=64 HALVES the per-CU L2 line-request
// count vs M=32 (the invariant limiter across R5-R9) and doubles MFMA per
// B-byte. Only ~10 barriers per launch (R6's 300-barrier failure avoided).
// Single-pass global dmax filter (margin 2.2, selection-exact).
__global__ __launch_bounds__(1024, 4) void vq_stage_kernel(
    const uint16_t* __restrict__ Ain, uint16_t* __restrict__ Aout,
    const uint16_t* __restrict__ cbh, const float* __restrict__ cbf,
    const float* __restrict__ csqG, float* __restrict__ cp,
    uint32_t key0, uint32_t key1) {
  constexpr int AST = 520;
  __shared__ uint16_t As[64 * AST];     // 66,560 B
  __shared__ float csqS[1024];          // 4 KB
  __shared__ float dmaxW[64 * 16];      // 4 KB
  __shared__ float thrS[64];
  __shared__ float wredV[64 * 16];      // 4 KB
  __shared__ int   wredI[64 * 16];      // 4 KB
  __shared__ int   idxS[64];
  __shared__ float cred[1024];          // 4 KB

  const int tid = threadIdx.x;
  const int w = tid >> 6;        // 0..15
  const int lane = tid & 63;
  const int quad = lane >> 4;
  const int col = lane & 15;
  const int blk = blockIdx.x;
  const int tokA = blk * 32;

  if (tid < 256) ((f32x4*)csqS)[tid] = ((const f32x4*)csqG)[tid];

  // stage A: 64 rows x 512 bf16
#pragma unroll
  for (int it = 0; it < 4; ++it) {
    int m = it * 1024 + tid;
    int r = m >> 6, c8 = m & 63;
    int token = (r < 32) ? (tokA + r) : (8192 + tokA + r - 32);
    *(uint4*)(As + r * AST + c8 * 8) =
        *(const uint4*)(Ain + (size_t)token * 512 + c8 * 8);
  }
  __syncthreads();

  f32x4 acc[4][4];  // [mt][nt] — wave's 64 codes x 64 tokens
#pragma unroll
  for (int mt = 0; mt < 4; ++mt)
#pragma unroll
    for (int nt = 0; nt < 4; ++nt) acc[mt][nt] = (f32x4){0.f, 0.f, 0.f, 0.f};

  // ---- barrier-free GEMM: 16 k-steps, B direct from L2, depth-2 ring ----
  const uint16_t* bb = cbh + (size_t)(w * 64 + col) * 512 + quad * 8;
  short8 bf[2][4];
#pragma unroll
  for (int j = 0; j < 4; ++j) bf[0][j] = *(const short8*)(bb + j * 8192);

#pragma unroll
  for (int ks = 0; ks < 16; ++ks) {
    if (ks < 15) {
#pragma unroll
      for (int j = 0; j < 4; ++j)
        bf[(ks + 1) & 1][j] = *(const short8*)(bb + j * 8192 + (ks + 1) * 32);
    }
#pragma unroll
    for (int mt = 0; mt < 4; ++mt) {
      short8 a = *(const short8*)(As + (mt * 16 + col) * AST + ks * 32 + quad * 8);
#pragma unroll
      for (int nt = 0; nt < 4; ++nt)
        acc[mt][nt] = __builtin_amdgcn_mfma_f32_16x16x32_bf16(a, bf[ks & 1][nt], acc[mt][nt], 0, 0, 0);
    }
  }

  // ---- per-token dmax: regs -> 16-lane shfl -> LDS over 16 waves ----
  float dmx[4][4];
#pragma unroll
  for (int mt = 0; mt < 4; ++mt)
#pragma unroll
    for (int rg = 0; rg < 4; ++rg) dmx[mt][rg] = -INFINITY;
#pragma unroll
  for (int nt = 0; nt < 4; ++nt) {
    const int code = w * 64 + nt * 16 + col;
    const float csqv = csqS[code];
#pragma unroll
    for (int mt = 0; mt < 4; ++mt)
#pragma unroll
      for (int rg = 0; rg < 4; ++rg)
        dmx[mt][rg] = fmaxf(dmx[mt][rg], acc[mt][nt][rg] * 2.f - csqv);
  }
#pragma unroll
  for (int mt = 0; mt < 4; ++mt)
#pragma unroll
    for (int rg = 0; rg < 4; ++rg) {
      float v = dmx[mt][rg];
#pragma unroll
      for (int m = 8; m >= 1; m >>= 1) v = fmaxf(v, __shfl_xor(v, m));
      if (col == 0) dmaxW[(mt * 16 + quad * 4 + rg) * 16 + w] = v;
    }
  __syncthreads();
  if (tid < 64) {
    float v = dmaxW[tid * 16];
#pragma unroll
    for (int j = 1; j < 16; ++j) v = fmaxf(v, dmaxW[tid * 16 + j]);
    thrS[tid] = v - 2.2f;
  }
  __syncthreads();

  float thr[4][4];
#pragma unroll
  for (int mt = 0; mt < 4; ++mt)
#pragma unroll
    for (int rg = 0; rg < 4; ++rg) thr[mt][rg] = thrS[mt * 16 + quad * 4 + rg];

  // ---- filtered gumbel + per-lane argmax (codes ascending per lane) ----
  float bestV[4][4];
  int bestI[4][4];
#pragma unroll
  for (int mt = 0; mt < 4; ++mt)
#pragma unroll
    for (int rg = 0; rg < 4; ++rg) { bestV[mt][rg] = -INFINITY; bestI[mt][rg] = 0; }

#pragma unroll
  for (int nt = 0; nt < 4; ++nt) {
    const int code = w * 64 + nt * 16 + col;
    const float csqv = csqS[code];
#pragma unroll
    for (int mh = 0; mh < 2; ++mh)
#pragma unroll
      for (int rg = 0; rg < 4; ++rg) {
        float d0 = acc[mh][nt][rg] * 2.f - csqv;
        float d1 = acc[mh + 2][nt][rg] * 2.f - csqv;
        bool c0 = d0 >= thr[mh][rg];
        bool c1 = d1 >= thr[mh + 2][rg];
        if (c0 || c1) {
          const int row0 = mh * 16 + quad * 4 + rg;
          const uint32_t n = (uint32_t)(tokA + row0) * 1024u + (uint32_t)code;
          uint32_t o0, o1;
          tf2x32(key0, key1, n, n + 8388608u, o0, o1);
          if (c0) {
            float s0 = d0 * 10.f + gumbel_bits(o0);
            if (s0 > bestV[mh][rg]) { bestV[mh][rg] = s0; bestI[mh][rg] = code; }
          }
          if (c1) {
            float s1 = d1 * 10.f + gumbel_bits(o1);
            if (s1 > bestV[mh + 2][rg]) { bestV[mh + 2][rg] = s1; bestI[mh + 2][rg] = code; }
          }
        }
      }
  }

  // 16-lane shfl argmax (tie: smaller code), then cross-wave via LDS
#pragma unroll
  for (int mt = 0; mt < 4; ++mt)
#pragma unroll
    for (int rg = 0; rg < 4; ++rg) {
      float v = bestV[mt][rg];
      int i = bestI[mt][rg];
#pragma unroll
      for (int m = 8; m >= 1; m >>= 1) {
        float vo = __shfl_xor(v, m);
        int io = __shfl_xor(i, m);
        if (vo > v || (vo == v && io < i)) { v = vo; i = io; }
      }
      if (col == 0) {
        const int row = mt * 16 + quad * 4 + rg;
        wredV[row * 16 + w] = v;
        wredI[row * 16 + w] = i;
      }
    }
  __syncthreads();
  if (tid < 64) {
    float v = wredV[tid * 16];
    int i = wredI[tid * 16];
#pragma unroll
    for (int j = 1; j < 16; ++j) {
      float vo = wredV[tid * 16 + j];
      int io = wredI[tid * 16 + j];
      if (vo > v || (vo == v && io < i)) { v = vo; i = io; }
    }
    idxS[tid] = i;
  }
  __syncthreads();

  // ---- update: r' = bf16(r - q) from LDS A -> global state; commit ----
  const int lr = tid >> 4;                 // 64 rows, 16 thr/row
  const int token = (lr < 32) ? (tokA + lr) : (8192 + tokA + lr - 32);
  const int code = idxS[lr];
  const float* qrow = cbf + (size_t)code * 512;
  const uint16_t* arow = As + lr * AST;
  uint16_t* orow = Aout + (size_t)token * 512;
  float s = 0.f;
#pragma unroll
  for (int it = 0; it < 8; ++it) {
    const int d = (tid & 15) * 4 + it * 64;
    float4 q = *(const float4*)(qrow + d);
    uint2 rp = *(const uint2*)(arow + d);
    union { uint16_t u[4]; uint2 v; } ri, ro;
    ri.v = rp;
    float r0 = bf2f(ri.u[0]), r1 = bf2f(ri.u[1]);
    float r2 = bf2f(ri.u[2]), r3 = bf2f(ri.u[3]);
    float d0 = q.x - r0, d1 = q.y - r1, d2 = q.z - r2, d3 = q.w - r3;
    s += d0 * d0 + d1 * d1 + d2 * d2 + d3 * d3;
    ro.u[0] = f2bf(r0 - q.x); ro.u[1] = f2bf(r1 - q.y);
    ro.u[2] = f2bf(r2 - q.z); ro.u[3] = f2bf(r3 - q.w);
    *(uint2*)(orow + d) = ro.v;
  }
  cred[tid] = s;
  __syncthreads();
  for (int st = 512; st > 0; st >>= 1) {
    if (tid < st) cred[tid] += cred[tid + st];
    __syncthreads();
  }
  if (tid == 0) cp[blk] = cred[0];
}

// ---------- finalize ----------
__global__ __launch_bounds__(256) void finalize_kernel(
    const float* __restrict__ cp, int ncp, const float* __restrict__ mp, int nmp,
    uint32_t* __restrict__ out) {
  __shared__ double sd[256];
  const int tid = threadIdx.x;
  double s = 0.0, sm = 0.0;
  for (int m = tid; m < ncp; m += 256) s += (double)cp[m];
  for (int m = tid; m < nmp; m += 256) sm += (double)mp[m];
  sd[tid] = s;
  __syncthreads();
  for (int st = 128; st > 0; st >>= 1) {
    if (tid < st) sd[tid] += sd[tid + st];
    __syncthreads();
  }
  double commit_total = sd[0];
  __syncthreads();
  sd[tid] = sm;
  __syncthreads();
  for (int st = 128; st > 0; st >>= 1) {
    if (tid < st) sd[tid] += sd[tid + st];
    __syncthreads();
  }
  if (tid == 0) {
    double commit = commit_total / (16384.0 * 512.0) / 8.0;
    double mse = sd[0] / (16384.0 * 100.0);
    float res = (float)(mse + commit);
    uint32_t fb = __float_as_uint(res);
    uint32_t lsb = (fb >> 16) & 1u;
    uint32_t hb = (fb + 0x7FFFu + lsb) >> 16;
    out[0] = (hb << 16) | hb;  // bf16 low 2B exact; f32 read within 0.4%
  }
}

// host-side threefry for stage keys
inline uint32_t h_rotl(uint32_t x, int r) { return (x << r) | (x >> (32 - r)); }
inline void h_tf2x32(uint32_t k0, uint32_t k1, uint32_t x0, uint32_t x1,
                     uint32_t* o0, uint32_t* o1) {
  const uint32_t k2 = k0 ^ k1 ^ 0x1BD11BDAu;
  const int R[2][4] = {{13, 15, 26, 6}, {17, 29, 16, 24}};
  const uint32_t ks[3] = {k0, k1, k2};
  x0 += k0; x1 += k1;
  for (int g = 0; g < 5; ++g) {
    for (int j = 0; j < 4; ++j) {
      x0 += x1; x1 = h_rotl(x1, R[g & 1][j]); x1 ^= x0;
    }
    x0 += ks[(g + 1) % 3];
    x1 += ks[(g + 2) % 3] + (uint32_t)(g + 1);
  }
  *o0 = x0; *o1 = x1;
}

}  // namespace

extern "C" void kernel_launch(void* const* d_in, const int* in_sizes, int n_in,
                              void* d_out, int out_size, void* d_ws, size_t ws_size,
                              hipStream_t stream) {
  char* ws = (char*)d_ws;
  uint16_t* z     = (uint16_t*)(ws + 0);           // 16,777,216
  uint16_t* h     = (uint16_t*)(ws + 16777216);    //  8,388,608
  uint16_t* rbf   = (uint16_t*)(ws + 25165824);    // 16,777,216 (state / dec_in)
  uint16_t* xbf   = (uint16_t*)(ws + 41943040);    //  4,194,304
  uint16_t* cbh   = (uint16_t*)(ws + 46137344);    //  1,048,576
  float*    cbf   = (float*)   (ws + 47185920);    //  2,097,152
  uint16_t* Wenc1 = (uint16_t*)(ws + 49283072);    //    196,608
  uint16_t* Wenc2 = (uint16_t*)(ws + 49479680);    //    786,432
  uint16_t* Wdec1 = (uint16_t*)(ws + 50266112);    //    786,432
  uint16_t* Wdec2 = (uint16_t*)(ws + 51052544);    //    196,608
  float*    eb1   = (float*)   (ws + 51249152);    //      1,024
  float*    eb2   = (float*)   (ws + 51250176);    //      2,048
  float*    db1   = (float*)   (ws + 51252224);    //      1,024
  float*    db2   = (float*)   (ws + 51253248);    //        512
  float*    csqG  = (float*)   (ws + 51253760);    //      4,096
  float*    cp    = (float*)   (ws + 51257856);    //      8,192 (8*256)
  float*    mp    = (float*)   (ws + 51266048);    //      1,024
  uint32_t* flag  = (uint32_t*)(ws + 51267072);    //          4

  detect_kernel<<<1, 256, 0, stream>>>((const uint32_t*)d_in[0], flag);

  cvt_f32_kernel<<<1, 256, 0, stream>>>(d_in[2], eb1, 256, flag);
  cvt_f32_kernel<<<2, 256, 0, stream>>>(d_in[4], eb2, 512, flag);
  cvt_f32_kernel<<<1, 256, 0, stream>>>(d_in[7], db1, 256, flag);
  cvt_f32_kernel<<<1, 256, 0, stream>>>(d_in[9], db2, 100, flag);
  cvt_f32_kernel<<<2048, 256, 0, stream>>>(d_in[5], cbf, 524288, flag);
  cvt_bf16_kernel<<<2048, 256, 0, stream>>>(d_in[5], cbh, 524288, flag);
  pack_w_kernel<<<(3 * 256 * 128 + 255) / 256, 256, 0, stream>>>(d_in[1], Wenc1, 256, 100, 256, 128, flag);
  pack_w_kernel<<<(3 * 512 * 256 + 255) / 256, 256, 0, stream>>>(d_in[3], Wenc2, 512, 256, 512, 256, flag);
  pack_w_kernel<<<(3 * 256 * 512 + 255) / 256, 256, 0, stream>>>(d_in[6], Wdec1, 256, 512, 256, 512, flag);
  pack_w_kernel<<<(3 * 128 * 256 + 255) / 256, 256, 0, stream>>>(d_in[8], Wdec2, 100, 256, 128, 256, flag);
  pack_x_kernel<<<(kTok * 128) / 256, 256, 0, stream>>>(d_in[0], xbf, flag);
  csq_kernel<<<kK / 4, 256, 0, stream>>>(cbf, csqG);

  conv_mfma_kernel<128, 256, 256, 0><<<256, 256, 0, stream>>>(
      xbf, Wenc1, eb1, h, nullptr, nullptr, flag, nullptr);
  conv_mfma_kernel<256, 512, 512, 0><<<256, 256, 0, stream>>>(
      h, Wenc2, eb2, z, nullptr, nullptr, flag, nullptr);

  for (int i = 0; i < 8; ++i) {
    uint32_t k0, k1;
    h_tf2x32(0u, 42u, 0u, (uint32_t)i, &k0, &k1);  // fold_in(key(42), i)
    vq_stage_kernel<<<256, 1024, 0, stream>>>(
        (i == 0) ? z : rbf, rbf, cbh, cbf, csqG, cp + i * 256, k0, k1);
  }

  dec_in_kernel<<<(kTok * kD / 4) / 256, 256, 0, stream>>>(z, rbf);
  conv_mfma_kernel<512, 256, 256, 0><<<256, 256, 0, stream>>>(
      rbf, Wdec1, db1, h, nullptr, nullptr, flag, nullptr);
  conv_mfma_kernel<256, 128, 100, 2><<<256, 256, 0, stream>>>(
      h, Wdec2, db2, nullptr, nullptr, d_in[0], flag, mp);

  finalize_kernel<<<1, 256, 0, stream>>>(cp, 8 * 256, mp, 256, (uint32_t*)d_out);
}